// Round 7
// baseline (465.730 us; speedup 1.0000x reference)
//
#include <hip/hip_runtime.h>

// 2-layer GCN, CSR-gather, bf16 payloads, zero global atomics.
//   hist(512-node buckets, 8192-edge blocks) -> scan -> [scatter ∥ gemm] -> sort
//   -> gather1 -> gather2 -> final.
// R6 lessons: gemm's per-thread row reads were uncoalesced (latency-bound at
// 2 TB/s) -> LDS-stage x tiles; int2 bucket entries had 3.7x write amplification
// -> pack to one int; sort at 196 blocks under-filled 256 CUs -> 512-node buckets.

#define TPB 256
#define CHUNK 8192          // edges per stage-1 block
#define BK_SHIFT 9
#define NPB 512             // nodes per bucket = 1 << BK_SHIFT

__device__ __forceinline__ float bf2f(unsigned short u) {
    union { unsigned int i; float f; } v; v.i = ((unsigned int)u) << 16; return v.f;
}
__device__ __forceinline__ unsigned short f2bf(float f) {
    union { float f; unsigned int i; } v; v.f = f;
    unsigned int r = v.i + 0x7fff + ((v.i >> 16) & 1);   // RNE
    return (unsigned short)(r >> 16);
}

// S1a: counts[bk*nblk + blk] = #edges in block blk with col>>9 == bk
__global__ __launch_bounds__(TPB) void hist_kernel(const int* __restrict__ col,
                                                   int* __restrict__ counts,
                                                   int E, int nblk, int nbuck) {
    __shared__ int hist[512];
    int t = threadIdx.x;
    for (int i = t; i < nbuck; i += TPB) hist[i] = 0;
    __syncthreads();
    int e0 = blockIdx.x * CHUNK;
    for (int i = t; i < CHUNK; i += TPB) {
        int e = e0 + i;
        if (e < E) atomicAdd(&hist[col[e] >> BK_SHIFT], 1);   // LDS atomic
    }
    __syncthreads();
    for (int i = t; i < nbuck; i += TPB) counts[i * nblk + blockIdx.x] = hist[i];
}

// generic exclusive scan, 3 kernels
__global__ __launch_bounds__(TPB) void scan1_kernel(const int* __restrict__ in,
                                                    int* __restrict__ out,
                                                    int* __restrict__ bsum, int L) {
    __shared__ int s[TPB];
    int t = threadIdx.x;
    int i = blockIdx.x * TPB + t;
    int d = (i < L) ? in[i] : 0;
    s[t] = d; __syncthreads();
    for (int off = 1; off < TPB; off <<= 1) {
        int v = (t >= off) ? s[t - off] : 0;
        __syncthreads();
        s[t] += v;
        __syncthreads();
    }
    if (i < L) out[i] = s[t] - d;
    if (t == TPB - 1) bsum[blockIdx.x] = s[t];
}

__global__ __launch_bounds__(1024) void scan2_kernel(int* __restrict__ bsum, int nb) {
    __shared__ int s[1024];
    int t = threadIdx.x;
    int v = (t < nb) ? bsum[t] : 0;
    s[t] = v; __syncthreads();
    for (int off = 1; off < 1024; off <<= 1) {
        int u = (t >= off) ? s[t - off] : 0;
        __syncthreads();
        s[t] += u;
        __syncthreads();
    }
    if (t < nb) bsum[t] = s[t] - v;
}

__global__ __launch_bounds__(TPB) void scan3g_kernel(int* __restrict__ out,
                                                     const int* __restrict__ bsum, int L) {
    int i = blockIdx.x * TPB + threadIdx.x;
    if (i < L) out[i] += bsum[blockIdx.x];
}

// S1c ∥ gemm, block-interleaved.  Scatter: bucketed[pos] = (local_col<<18)|row.
// Gemm: LDS-staged x tiles (256 nodes/block, 16-col chunks, pad-17 readback);
// W1 read wave-uniform from global (scalar-pipe loads).
__global__ __launch_bounds__(TPB) void s1c_gemm_kernel(
        const int* __restrict__ row, const int* __restrict__ col,
        const int* __restrict__ cbase, int E, int nblk, int nbuck,
        int* __restrict__ bucketed,
        const float* __restrict__ x, const float* __restrict__ W1,
        float* __restrict__ h1, int N, int nbg) {
    __shared__ float smem[256 * 17];          // gemm: xs ; scatter: cur (cast)
    int b = (int)blockIdx.x, t = threadIdx.x;
    int M = min(nblk, nbg);
    int role, id;
    if (b < 2 * M) { role = b & 1; id = b >> 1; }
    else           { role = (nblk > nbg) ? 0 : 1; id = b - M; }

    if (role == 0) {                         // scatter to bucket-major
        int* cur = (int*)smem;
        for (int i = t; i < nbuck; i += TPB) cur[i] = cbase[i * nblk + id];
        __syncthreads();
        int e0 = id * CHUNK;
        for (int i = t; i < CHUNK; i += TPB) {
            int e = e0 + i;
            if (e < E) {
                int c = col[e];
                int pos = atomicAdd(&cur[c >> BK_SHIFT], 1);   // LDS atomic
                bucketed[pos] = ((c & (NPB - 1)) << 18) | row[e];
            }
        }
        return;
    }
    // gemm: h1[n] = x[n] @ W1
    float* xs = smem;
    int n0 = id * TPB;
    int n = n0 + t;
    int nrows = min(TPB, N - n0);
    float acc[16];
#pragma unroll
    for (int k = 0; k < 16; ++k) acc[k] = 0.f;
#pragma unroll 1
    for (int ch = 0; ch < 8; ++ch) {
        __syncthreads();
        for (int f = t; f < nrows * 4; f += TPB) {
            int r = f >> 2, q = f & 3;
            const float* src = x + (size_t)(n0 + r) * 128 + ch * 16 + q * 4;
            float4 v = *(const float4*)src;
            float* dst = &xs[r * 17 + q * 4];
            dst[0] = v.x; dst[1] = v.y; dst[2] = v.z; dst[3] = v.w;
        }
        __syncthreads();
        if (n < N) {
            const float* xr = &xs[t * 17];
#pragma unroll
            for (int c = 0; c < 16; ++c) {
                float xc = xr[c];
                const float4* w4 = (const float4*)(W1 + (size_t)(ch * 16 + c) * 16);
                float4 wa = w4[0], wb = w4[1], wc = w4[2], wd = w4[3];
                acc[0]  = fmaf(xc, wa.x, acc[0]);  acc[1]  = fmaf(xc, wa.y, acc[1]);
                acc[2]  = fmaf(xc, wa.z, acc[2]);  acc[3]  = fmaf(xc, wa.w, acc[3]);
                acc[4]  = fmaf(xc, wb.x, acc[4]);  acc[5]  = fmaf(xc, wb.y, acc[5]);
                acc[6]  = fmaf(xc, wb.z, acc[6]);  acc[7]  = fmaf(xc, wb.w, acc[7]);
                acc[8]  = fmaf(xc, wc.x, acc[8]);  acc[9]  = fmaf(xc, wc.y, acc[9]);
                acc[10] = fmaf(xc, wc.z, acc[10]); acc[11] = fmaf(xc, wc.w, acc[11]);
                acc[12] = fmaf(xc, wd.x, acc[12]); acc[13] = fmaf(xc, wd.y, acc[13]);
                acc[14] = fmaf(xc, wd.z, acc[14]); acc[15] = fmaf(xc, wd.w, acc[15]);
            }
        }
    }
    if (n < N) {
        float4* o = (float4*)(h1 + (size_t)n * 16);
        o[0] = make_float4(acc[0], acc[1], acc[2], acc[3]);
        o[1] = make_float4(acc[4], acc[5], acc[6], acc[7]);
        o[2] = make_float4(acc[8], acc[9], acc[10], acc[11]);
        o[3] = make_float4(acc[12], acc[13], acc[14], acc[15]);
    }
}

// S2: one block per 512-node bucket: counting sort, emit csr/offs/dinv,
// h1p = bf16(dinv*h1).
__global__ __launch_bounds__(TPB) void sort_kernel(
        const int* __restrict__ bucketed, const int* __restrict__ cbase,
        int E, int nblk, int nbuck,
        int* __restrict__ csr, int* __restrict__ offs, float* __restrict__ dinv,
        const float* __restrict__ h1, unsigned short* __restrict__ h1p, int N) {
    __shared__ int lhist[NPB];
    __shared__ int part[TPB];
    __shared__ float sdinv[NPB];
    int bk = blockIdx.x, t = threadIdx.x;
    int n0 = bk << BK_SHIFT;
    int n1 = min(n0 + NPB, N);
    int e0 = cbase[bk * nblk];
    int e1 = (bk + 1 < nbuck) ? cbase[(bk + 1) * nblk] : E;

    lhist[t] = 0; lhist[t + TPB] = 0;
    __syncthreads();
    for (int i = e0 + t; i < e1; i += TPB)
        atomicAdd(&lhist[bucketed[i] >> 18], 1);               // LDS atomic
    __syncthreads();

    int base = t * 2;
    int c0 = lhist[base], c1 = lhist[base + 1];
    int s = c0 + c1;
    part[t] = s;
    __syncthreads();
    for (int off = 1; off < TPB; off <<= 1) {
        int v = (t >= off) ? part[t - off] : 0;
        __syncthreads();
        part[t] += v;
        __syncthreads();
    }
    int o0 = e0 + part[t] - s;
    int o1 = o0 + c0;
    lhist[base] = o0; lhist[base + 1] = o1;
    sdinv[base]     = rsqrtf((float)c0 + 1.0f);
    sdinv[base + 1] = rsqrtf((float)c1 + 1.0f);
    int n = n0 + base;
    if (n + 0 < N) { offs[n + 0] = o0; dinv[n + 0] = sdinv[base]; }
    if (n + 1 < N) { offs[n + 1] = o1; dinv[n + 1] = sdinv[base + 1]; }
    __syncthreads();

    for (int i = e0 + t; i < e1; i += TPB) {
        int v = bucketed[i];
        int pos = atomicAdd(&lhist[v >> 18], 1);               // LDS atomic
        csr[pos] = v & 0x3FFFF;
    }
    int nq = (n1 - n0) * 4;
    for (int i = t; i < nq; i += TPB) {
        float dv = sdinv[i >> 2];
        float4 v = ((const float4*)h1)[(size_t)n0 * 4 + i];
        ((ushort4*)h1p)[(size_t)n0 * 4 + i] =
            make_ushort4(f2bf(v.x * dv), f2bf(v.y * dv), f2bf(v.z * dv), f2bf(v.w * dv));
    }
    if (bk == 0 && t == 0) offs[N] = E;
}

// gather1: one WAVE per node (16 feats x 4 edges), shfl-reduce across edge-subgroups.
// h2p[c] = bf16( dinv[c]*relu( dinv[c]*(sum h1p[src] + h1p[c]) + b1 ) )
__global__ __launch_bounds__(TPB) void gather1_kernel(const int* __restrict__ csr,
                                                      const int* __restrict__ offs,
                                                      const unsigned short* __restrict__ h1p,
                                                      const float* __restrict__ dinv,
                                                      const float* __restrict__ b1,
                                                      unsigned short* __restrict__ h2p, int N) {
    int t = threadIdx.x;
    int c = blockIdx.x * 4 + (t >> 6);
    int lane = t & 63;
    int k = lane & 15, sub = lane >> 4;
    if (c >= N) return;
    int p0 = offs[c], p1 = offs[c + 1];
    float acc = 0.f;
    for (int p = p0; p < p1; p += 16) {
        int rem = p1 - p;
        float v[4];
#pragma unroll
        for (int u = 0; u < 4; ++u) {
            int idx = p + u * 4 + sub;
            int sidx = csr[min(idx, p1 - 1)];
            v[u] = bf2f(h1p[(size_t)sidx * 16 + k]);
        }
#pragma unroll
        for (int u = 0; u < 4; ++u) acc += (u * 4 + sub < rem) ? v[u] : 0.f;
    }
    acc += __shfl_down(acc, 32);
    acc += __shfl_down(acc, 16);
    if (sub == 0) {
        float dc = dinv[c];
        float self = bf2f(h1p[(size_t)c * 16 + k]);
        float a = fmaf(dc, acc + self, b1[k]);
        h2p[(size_t)c * 16 + k] = f2bf(dc * fmaxf(a, 0.f));
    }
}

// gather2: a2[c] = dinv[c]*(sum h2p[src] + h2p[c])   (fp32 out)
__global__ __launch_bounds__(TPB) void gather2_kernel(const int* __restrict__ csr,
                                                      const int* __restrict__ offs,
                                                      const unsigned short* __restrict__ h2p,
                                                      const float* __restrict__ dinv,
                                                      float* __restrict__ a2, int N) {
    int t = threadIdx.x;
    int c = blockIdx.x * 4 + (t >> 6);
    int lane = t & 63;
    int k = lane & 15, sub = lane >> 4;
    if (c >= N) return;
    int p0 = offs[c], p1 = offs[c + 1];
    float acc = 0.f;
    for (int p = p0; p < p1; p += 16) {
        int rem = p1 - p;
        float v[4];
#pragma unroll
        for (int u = 0; u < 4; ++u) {
            int idx = p + u * 4 + sub;
            int sidx = csr[min(idx, p1 - 1)];
            v[u] = bf2f(h2p[(size_t)sidx * 16 + k]);
        }
#pragma unroll
        for (int u = 0; u < 4; ++u) acc += (u * 4 + sub < rem) ? v[u] : 0.f;
    }
    acc += __shfl_down(acc, 32);
    acc += __shfl_down(acc, 16);
    if (sub == 0) {
        float self = bf2f(h2p[(size_t)c * 16 + k]);
        a2[(size_t)c * 16 + k] = dinv[c] * (acc + self);
    }
}

// final: out[g] += a2[n]@W2 + b2, pooled over sorted batch; 64 nodes per wave
__global__ __launch_bounds__(TPB) void final_kernel(const float* __restrict__ a2,
                                                    const float* __restrict__ W2,
                                                    const float* __restrict__ b2,
                                                    const int* __restrict__ batch,
                                                    float* __restrict__ out, int N) {
    __shared__ float w2s[16 * 64];
    int t = threadIdx.x;
    for (int i = t; i < 16 * 64; i += TPB) w2s[i] = W2[i];
    __syncthreads();

    int wave = t >> 6, lane = t & 63;
    int n0 = blockIdx.x * 256 + wave * 64;
    float b2k = b2[lane];
    int g_cur = -1;
    float acc = 0.f;
    for (int i = 0; i < 64; ++i) {
        int n = n0 + i;
        if (n >= N) break;
        const float* ar = a2 + (size_t)n * 16;
        float val = b2k;
#pragma unroll
        for (int j = 0; j < 16; ++j) val = fmaf(ar[j], w2s[j * 64 + lane], val);
        int g = batch[n];
        if (g != g_cur) {
            if (g_cur >= 0) atomicAdd(&out[(size_t)g_cur * 64 + lane], acc);
            acc = 0.f;
            g_cur = g;
        }
        acc += val;
    }
    if (g_cur >= 0) atomicAdd(&out[(size_t)g_cur * 64 + lane], acc);
}

static inline size_t align64(size_t v) { return (v + 63) & ~(size_t)63; }

extern "C" void kernel_launch(void* const* d_in, const int* in_sizes, int n_in,
                              void* d_out, int out_size, void* d_ws, size_t ws_size,
                              hipStream_t stream) {
    const float* x     = (const float*)d_in[0];
    const int*   ei    = (const int*)d_in[1];
    const int*   batch = (const int*)d_in[2];
    const float* W1    = (const float*)d_in[3];
    const float* b1    = (const float*)d_in[4];
    const float* W2    = (const float*)d_in[5];
    const float* b2    = (const float*)d_in[6];

    const int N = in_sizes[0] / 128;
    const int E = in_sizes[1] / 2;
    const int* row = ei;        // edge_index[0]
    const int* col = ei + E;    // edge_index[1]

    const int NBLK  = (E + CHUNK - 1) / CHUNK;       // 391
    const int NBUCK = (N + NPB - 1) / NPB;           // 391 (<=512)
    const int L     = NBUCK * NBLK;                  // 152881
    const int NBS   = (L + TPB - 1) / TPB;           // 598 (<=1024)
    const int NBG   = (N + TPB - 1) / TPB;           // 782

    char* p = (char*)d_ws;
    int*            counts   = (int*)p;            p += align64((size_t)L * 4);
    int*            bsum     = (int*)p;            p += align64(1024 * 4);
    int*            bucketed = (int*)p;            p += align64((size_t)E * 4);
    int*            csr      = (int*)p;            p += align64((size_t)E * 4);
    int*            offs     = (int*)p;            p += align64((size_t)(N + 1) * 4);
    float*          dinv     = (float*)p;          p += align64((size_t)N * 4);
    float*          h1       = (float*)p;          p += align64((size_t)N * 16 * 4);
    unsigned short* h1p      = (unsigned short*)p; p += align64((size_t)N * 16 * 2);
    unsigned short* h2p      = (unsigned short*)p; p += align64((size_t)N * 16 * 2);
    float*          a2       = h1;                 // h1 dead after sort_kernel
    float*          out      = (float*)d_out;

    hipMemsetAsync(out, 0, (size_t)out_size * sizeof(float), stream);

    hist_kernel<<<NBLK, TPB, 0, stream>>>(col, counts, E, NBLK, NBUCK);
    scan1_kernel<<<NBS, TPB, 0, stream>>>(counts, counts, bsum, L);
    scan2_kernel<<<1, 1024, 0, stream>>>(bsum, NBS);
    scan3g_kernel<<<NBS, TPB, 0, stream>>>(counts, bsum, L);
    s1c_gemm_kernel<<<NBLK + NBG, TPB, 0, stream>>>(row, col, counts, E, NBLK, NBUCK,
                                                    bucketed, x, W1, h1, N, NBG);
    sort_kernel<<<NBUCK, TPB, 0, stream>>>(bucketed, counts, E, NBLK, NBUCK,
                                           csr, offs, dinv, h1, h1p, N);
    gather1_kernel<<<(N + 3) / 4, TPB, 0, stream>>>(csr, offs, h1p, dinv, b1, h2p, N);
    gather2_kernel<<<(N + 3) / 4, TPB, 0, stream>>>(csr, offs, h2p, dinv, a2, N);
    final_kernel<<<(N + 255) / 256, TPB, 0, stream>>>(a2, W2, b2, batch, out, N);
}

// Round 8
// 397.184 us; speedup vs baseline: 1.1726x; 1.1726x over previous
//
#include <hip/hip_runtime.h>

// 2-layer GCN, CSR-gather, bf16 payloads, zero global atomics.
//   hist(512-node buckets) -> scan -> [scatter ∥ gemm] -> sort -> gather1
//   -> gather2 -> final.
// R7 lessons: LDS-tiling the gemm quadrupled bank conflicts and halved
// occupancy -> keep per-thread row reads (latency hidden by scatter waves).
// One-wave-per-node gathers cut per-lane ILP 16->4 and regressed -> 16
// lanes/node with 32 edges in flight per iteration.

#define TPB 256
#define CHUNK 8192          // edges per stage-1 block
#define BK_SHIFT 9
#define NPB 512             // nodes per bucket = 1 << BK_SHIFT

__device__ __forceinline__ float bf2f(unsigned short u) {
    union { unsigned int i; float f; } v; v.i = ((unsigned int)u) << 16; return v.f;
}
__device__ __forceinline__ unsigned short f2bf(float f) {
    union { float f; unsigned int i; } v; v.f = f;
    unsigned int r = v.i + 0x7fff + ((v.i >> 16) & 1);   // RNE
    return (unsigned short)(r >> 16);
}

// S1a: counts[bk*nblk + blk] = #edges in block blk with col>>9 == bk
__global__ __launch_bounds__(TPB) void hist_kernel(const int* __restrict__ col,
                                                   int* __restrict__ counts,
                                                   int E, int nblk, int nbuck) {
    __shared__ int hist[512];
    int t = threadIdx.x;
    for (int i = t; i < nbuck; i += TPB) hist[i] = 0;
    __syncthreads();
    int e0 = blockIdx.x * CHUNK;
    for (int i = t; i < CHUNK; i += TPB) {
        int e = e0 + i;
        if (e < E) atomicAdd(&hist[col[e] >> BK_SHIFT], 1);   // LDS atomic
    }
    __syncthreads();
    for (int i = t; i < nbuck; i += TPB) counts[i * nblk + blockIdx.x] = hist[i];
}

// generic exclusive scan, 3 kernels
__global__ __launch_bounds__(TPB) void scan1_kernel(const int* __restrict__ in,
                                                    int* __restrict__ out,
                                                    int* __restrict__ bsum, int L) {
    __shared__ int s[TPB];
    int t = threadIdx.x;
    int i = blockIdx.x * TPB + t;
    int d = (i < L) ? in[i] : 0;
    s[t] = d; __syncthreads();
    for (int off = 1; off < TPB; off <<= 1) {
        int v = (t >= off) ? s[t - off] : 0;
        __syncthreads();
        s[t] += v;
        __syncthreads();
    }
    if (i < L) out[i] = s[t] - d;
    if (t == TPB - 1) bsum[blockIdx.x] = s[t];
}

__global__ __launch_bounds__(1024) void scan2_kernel(int* __restrict__ bsum, int nb) {
    __shared__ int s[1024];
    int t = threadIdx.x;
    int v = (t < nb) ? bsum[t] : 0;
    s[t] = v; __syncthreads();
    for (int off = 1; off < 1024; off <<= 1) {
        int u = (t >= off) ? s[t - off] : 0;
        __syncthreads();
        s[t] += u;
        __syncthreads();
    }
    if (t < nb) bsum[t] = s[t] - v;
}

__global__ __launch_bounds__(TPB) void scan3g_kernel(int* __restrict__ out,
                                                     const int* __restrict__ bsum, int L) {
    int i = blockIdx.x * TPB + threadIdx.x;
    if (i < L) out[i] += bsum[blockIdx.x];
}

// S1c ∥ gemm, block-interleaved.  Scatter: bucketed[pos] = (local_col<<18)|row.
// Gemm (R6 form): per-thread x row, W1 in LDS, 16 accumulators.
__global__ __launch_bounds__(TPB) void s1c_gemm_kernel(
        const int* __restrict__ row, const int* __restrict__ col,
        const int* __restrict__ cbase, int E, int nblk, int nbuck,
        int* __restrict__ bucketed,
        const float* __restrict__ x, const float* __restrict__ W1,
        float* __restrict__ h1, int N, int nbg) {
    __shared__ int cur[NPB];
    __shared__ float w1s[128 * 16];
    int b = (int)blockIdx.x, t = threadIdx.x;
    int M = min(nblk, nbg);
    int role, id;
    if (b < 2 * M) { role = b & 1; id = b >> 1; }
    else           { role = (nblk > nbg) ? 0 : 1; id = b - M; }

    if (role == 0) {                         // scatter to bucket-major
        for (int i = t; i < nbuck; i += TPB) cur[i] = cbase[i * nblk + id];
        __syncthreads();
        int e0 = id * CHUNK;
        for (int i = t; i < CHUNK; i += TPB) {
            int e = e0 + i;
            if (e < E) {
                int c = col[e];
                int pos = atomicAdd(&cur[c >> BK_SHIFT], 1);   // LDS atomic
                bucketed[pos] = ((c & (NPB - 1)) << 18) | row[e];
            }
        }
        return;
    }
    // gemm: h1[n] = x[n] @ W1, one thread per node, W1 in LDS
    for (int i = t; i < 128 * 16; i += TPB) w1s[i] = W1[i];
    __syncthreads();
    int n = id * TPB + t;
    if (n >= N) return;
    const float4* xr = (const float4*)(x + (size_t)n * 128);
    float acc[16];
#pragma unroll
    for (int k = 0; k < 16; ++k) acc[k] = 0.f;
#pragma unroll 1
    for (int g = 0; g < 8; ++g) {
        float4 v0 = xr[g * 4 + 0], v1 = xr[g * 4 + 1];
        float4 v2 = xr[g * 4 + 2], v3 = xr[g * 4 + 3];
        float xv[16] = {v0.x, v0.y, v0.z, v0.w, v1.x, v1.y, v1.z, v1.w,
                        v2.x, v2.y, v2.z, v2.w, v3.x, v3.y, v3.z, v3.w};
#pragma unroll
        for (int cc = 0; cc < 16; ++cc) {
            const float4* w4 = (const float4*)&w1s[(g * 16 + cc) * 16];
            float4 wa = w4[0], wb = w4[1], wc = w4[2], wd = w4[3];
            float xc = xv[cc];
            acc[0]  = fmaf(xc, wa.x, acc[0]);  acc[1]  = fmaf(xc, wa.y, acc[1]);
            acc[2]  = fmaf(xc, wa.z, acc[2]);  acc[3]  = fmaf(xc, wa.w, acc[3]);
            acc[4]  = fmaf(xc, wb.x, acc[4]);  acc[5]  = fmaf(xc, wb.y, acc[5]);
            acc[6]  = fmaf(xc, wb.z, acc[6]);  acc[7]  = fmaf(xc, wb.w, acc[7]);
            acc[8]  = fmaf(xc, wc.x, acc[8]);  acc[9]  = fmaf(xc, wc.y, acc[9]);
            acc[10] = fmaf(xc, wc.z, acc[10]); acc[11] = fmaf(xc, wc.w, acc[11]);
            acc[12] = fmaf(xc, wd.x, acc[12]); acc[13] = fmaf(xc, wd.y, acc[13]);
            acc[14] = fmaf(xc, wd.z, acc[14]); acc[15] = fmaf(xc, wd.w, acc[15]);
        }
    }
    float4* o = (float4*)(h1 + (size_t)n * 16);
    o[0] = make_float4(acc[0], acc[1], acc[2], acc[3]);
    o[1] = make_float4(acc[4], acc[5], acc[6], acc[7]);
    o[2] = make_float4(acc[8], acc[9], acc[10], acc[11]);
    o[3] = make_float4(acc[12], acc[13], acc[14], acc[15]);
}

// S2: one block per 512-node bucket: counting sort, emit csr/offs/dinv,
// h1p = bf16(dinv*h1).
__global__ __launch_bounds__(TPB) void sort_kernel(
        const int* __restrict__ bucketed, const int* __restrict__ cbase,
        int E, int nblk, int nbuck,
        int* __restrict__ csr, int* __restrict__ offs, float* __restrict__ dinv,
        const float* __restrict__ h1, unsigned short* __restrict__ h1p, int N) {
    __shared__ int lhist[NPB];
    __shared__ int part[TPB];
    __shared__ float sdinv[NPB];
    int bk = blockIdx.x, t = threadIdx.x;
    int n0 = bk << BK_SHIFT;
    int n1 = min(n0 + NPB, N);
    int e0 = cbase[bk * nblk];
    int e1 = (bk + 1 < nbuck) ? cbase[(bk + 1) * nblk] : E;

    lhist[t] = 0; lhist[t + TPB] = 0;
    __syncthreads();
    for (int i = e0 + t; i < e1; i += TPB)
        atomicAdd(&lhist[bucketed[i] >> 18], 1);               // LDS atomic
    __syncthreads();

    int base = t * 2;
    int c0 = lhist[base], c1 = lhist[base + 1];
    int s = c0 + c1;
    part[t] = s;
    __syncthreads();
    for (int off = 1; off < TPB; off <<= 1) {
        int v = (t >= off) ? part[t - off] : 0;
        __syncthreads();
        part[t] += v;
        __syncthreads();
    }
    int o0 = e0 + part[t] - s;
    int o1 = o0 + c0;
    lhist[base] = o0; lhist[base + 1] = o1;
    sdinv[base]     = rsqrtf((float)c0 + 1.0f);
    sdinv[base + 1] = rsqrtf((float)c1 + 1.0f);
    int n = n0 + base;
    if (n + 0 < N) { offs[n + 0] = o0; dinv[n + 0] = sdinv[base]; }
    if (n + 1 < N) { offs[n + 1] = o1; dinv[n + 1] = sdinv[base + 1]; }
    __syncthreads();

    for (int i = e0 + t; i < e1; i += TPB) {
        int v = bucketed[i];
        int pos = atomicAdd(&lhist[v >> 18], 1);               // LDS atomic
        csr[pos] = v & 0x3FFFF;
    }
    int nq = (n1 - n0) * 4;
    for (int i = t; i < nq; i += TPB) {
        float dv = sdinv[i >> 2];
        float4 v = ((const float4*)h1)[(size_t)n0 * 4 + i];
        ((ushort4*)h1p)[(size_t)n0 * 4 + i] =
            make_ushort4(f2bf(v.x * dv), f2bf(v.y * dv), f2bf(v.z * dv), f2bf(v.w * dv));
    }
    if (bk == 0 && t == 0) offs[N] = E;
}

// gather1: 16 lanes/node, 32 edges in flight per iteration.
// h2p[c] = bf16( dinv[c]*relu( dinv[c]*(sum h1p[src] + h1p[c]) + b1 ) )
__global__ __launch_bounds__(TPB) void gather1_kernel(const int* __restrict__ csr,
                                                      const int* __restrict__ offs,
                                                      const unsigned short* __restrict__ h1p,
                                                      const float* __restrict__ dinv,
                                                      const float* __restrict__ b1,
                                                      unsigned short* __restrict__ h2p, int N) {
    int t = threadIdx.x;
    int c = blockIdx.x * 16 + (t >> 4);
    int k = t & 15;
    if (c >= N) return;
    int p0 = offs[c], p1 = offs[c + 1];
    float acc = 0.f;
    for (int p = p0; p < p1; p += 32) {
        int s0 = csr[min(p + k, p1 - 1)];
        int s1 = csr[min(p + 16 + k, p1 - 1)];
        int rem = p1 - p;
        float v[32];
#pragma unroll
        for (int j = 0; j < 16; ++j) {
            int sj = __shfl(s0, j, 16);
            v[j] = bf2f(h1p[(size_t)sj * 16 + k]);
        }
#pragma unroll
        for (int j = 0; j < 16; ++j) {
            int sj = __shfl(s1, j, 16);
            v[16 + j] = bf2f(h1p[(size_t)sj * 16 + k]);
        }
#pragma unroll
        for (int j = 0; j < 32; ++j) acc += (j < rem) ? v[j] : 0.f;
    }
    float dc = dinv[c];
    float self = bf2f(h1p[(size_t)c * 16 + k]);
    float a = fmaf(dc, acc + self, b1[k]);
    h2p[(size_t)c * 16 + k] = f2bf(dc * fmaxf(a, 0.f));
}

// gather2: a2[c] = dinv[c]*(sum h2p[src] + h2p[c])   (fp32 out)
__global__ __launch_bounds__(TPB) void gather2_kernel(const int* __restrict__ csr,
                                                      const int* __restrict__ offs,
                                                      const unsigned short* __restrict__ h2p,
                                                      const float* __restrict__ dinv,
                                                      float* __restrict__ a2, int N) {
    int t = threadIdx.x;
    int c = blockIdx.x * 16 + (t >> 4);
    int k = t & 15;
    if (c >= N) return;
    int p0 = offs[c], p1 = offs[c + 1];
    float acc = 0.f;
    for (int p = p0; p < p1; p += 32) {
        int s0 = csr[min(p + k, p1 - 1)];
        int s1 = csr[min(p + 16 + k, p1 - 1)];
        int rem = p1 - p;
        float v[32];
#pragma unroll
        for (int j = 0; j < 16; ++j) {
            int sj = __shfl(s0, j, 16);
            v[j] = bf2f(h2p[(size_t)sj * 16 + k]);
        }
#pragma unroll
        for (int j = 0; j < 16; ++j) {
            int sj = __shfl(s1, j, 16);
            v[16 + j] = bf2f(h2p[(size_t)sj * 16 + k]);
        }
#pragma unroll
        for (int j = 0; j < 32; ++j) acc += (j < rem) ? v[j] : 0.f;
    }
    float self = bf2f(h2p[(size_t)c * 16 + k]);
    a2[(size_t)c * 16 + k] = dinv[c] * (acc + self);
}

// final: out[g] += a2[n]@W2 + b2, pooled over sorted batch; 64 nodes per wave
__global__ __launch_bounds__(TPB) void final_kernel(const float* __restrict__ a2,
                                                    const float* __restrict__ W2,
                                                    const float* __restrict__ b2,
                                                    const int* __restrict__ batch,
                                                    float* __restrict__ out, int N) {
    __shared__ float w2s[16 * 64];
    int t = threadIdx.x;
    for (int i = t; i < 16 * 64; i += TPB) w2s[i] = W2[i];
    __syncthreads();

    int wave = t >> 6, lane = t & 63;
    int n0 = blockIdx.x * 256 + wave * 64;
    float b2k = b2[lane];
    int g_cur = -1;
    float acc = 0.f;
    for (int i = 0; i < 64; ++i) {
        int n = n0 + i;
        if (n >= N) break;
        const float* ar = a2 + (size_t)n * 16;
        float val = b2k;
#pragma unroll
        for (int j = 0; j < 16; ++j) val = fmaf(ar[j], w2s[j * 64 + lane], val);
        int g = batch[n];
        if (g != g_cur) {
            if (g_cur >= 0) atomicAdd(&out[(size_t)g_cur * 64 + lane], acc);
            acc = 0.f;
            g_cur = g;
        }
        acc += val;
    }
    if (g_cur >= 0) atomicAdd(&out[(size_t)g_cur * 64 + lane], acc);
}

static inline size_t align64(size_t v) { return (v + 63) & ~(size_t)63; }

extern "C" void kernel_launch(void* const* d_in, const int* in_sizes, int n_in,
                              void* d_out, int out_size, void* d_ws, size_t ws_size,
                              hipStream_t stream) {
    const float* x     = (const float*)d_in[0];
    const int*   ei    = (const int*)d_in[1];
    const int*   batch = (const int*)d_in[2];
    const float* W1    = (const float*)d_in[3];
    const float* b1    = (const float*)d_in[4];
    const float* W2    = (const float*)d_in[5];
    const float* b2    = (const float*)d_in[6];

    const int N = in_sizes[0] / 128;
    const int E = in_sizes[1] / 2;
    const int* row = ei;        // edge_index[0]
    const int* col = ei + E;    // edge_index[1]

    const int NBLK  = (E + CHUNK - 1) / CHUNK;       // 391
    const int NBUCK = (N + NPB - 1) / NPB;           // 391 (<=512)
    const int L     = NBUCK * NBLK;                  // 152881
    const int NBS   = (L + TPB - 1) / TPB;           // 598 (<=1024)
    const int NBG   = (N + TPB - 1) / TPB;           // 782

    char* p = (char*)d_ws;
    int*            counts   = (int*)p;            p += align64((size_t)L * 4);
    int*            bsum     = (int*)p;            p += align64(1024 * 4);
    int*            bucketed = (int*)p;            p += align64((size_t)E * 4);
    int*            csr      = (int*)p;            p += align64((size_t)E * 4);
    int*            offs     = (int*)p;            p += align64((size_t)(N + 1) * 4);
    float*          dinv     = (float*)p;          p += align64((size_t)N * 4);
    float*          h1       = (float*)p;          p += align64((size_t)N * 16 * 4);
    unsigned short* h1p      = (unsigned short*)p; p += align64((size_t)N * 16 * 2);
    unsigned short* h2p      = (unsigned short*)p; p += align64((size_t)N * 16 * 2);
    float*          a2       = h1;                 // h1 dead after sort_kernel
    float*          out      = (float*)d_out;

    hipMemsetAsync(out, 0, (size_t)out_size * sizeof(float), stream);

    hist_kernel<<<NBLK, TPB, 0, stream>>>(col, counts, E, NBLK, NBUCK);
    scan1_kernel<<<NBS, TPB, 0, stream>>>(counts, counts, bsum, L);
    scan2_kernel<<<1, 1024, 0, stream>>>(bsum, NBS);
    scan3g_kernel<<<NBS, TPB, 0, stream>>>(counts, bsum, L);
    s1c_gemm_kernel<<<NBLK + NBG, TPB, 0, stream>>>(row, col, counts, E, NBLK, NBUCK,
                                                    bucketed, x, W1, h1, N, NBG);
    sort_kernel<<<NBUCK, TPB, 0, stream>>>(bucketed, counts, E, NBLK, NBUCK,
                                           csr, offs, dinv, h1, h1p, N);
    gather1_kernel<<<(N + 15) / 16, TPB, 0, stream>>>(csr, offs, h1p, dinv, b1, h2p, N);
    gather2_kernel<<<(N + 15) / 16, TPB, 0, stream>>>(csr, offs, h2p, dinv, a2, N);
    final_kernel<<<(N + 255) / 256, TPB, 0, stream>>>(a2, W2, b2, batch, out, N);
}

// Round 9
// 374.543 us; speedup vs baseline: 1.2435x; 1.0604x over previous
//
#include <hip/hip_runtime.h>

// 2-layer GCN, CSR-gather, bf16 payloads, zero global atomics.
//   hist(512-node buckets) -> scan -> [scatter ∥ gemm, 1:1 interleave] -> sort
//   -> gather1 -> gather2 -> final.
// R8 lesson: CHUNK=8192 broke the 1:1 scatter/gemm interleave (391 vs 782
// blocks) -> scatter-heavy resident mix + unhidden gemm tail; s1c 93.6->114.8us.
// Restore CHUNK=4096; scan2 generalized to 2 elems/thread for the bigger scan.
// Keep: 512-node buckets (sort fills 256 CUs), packed 1-int bucket entries,
// 32-edges-in-flight gathers (R7 lesson: per-lane ILP is the gather currency).

#define TPB 256
#define CHUNK 4096          // edges per stage-1 block (1:1 with gemm blocks)
#define BK_SHIFT 9
#define NPB 512             // nodes per bucket = 1 << BK_SHIFT

__device__ __forceinline__ float bf2f(unsigned short u) {
    union { unsigned int i; float f; } v; v.i = ((unsigned int)u) << 16; return v.f;
}
__device__ __forceinline__ unsigned short f2bf(float f) {
    union { float f; unsigned int i; } v; v.f = f;
    unsigned int r = v.i + 0x7fff + ((v.i >> 16) & 1);   // RNE
    return (unsigned short)(r >> 16);
}

// S1a: counts[bk*nblk + blk] = #edges in block blk with col>>9 == bk
__global__ __launch_bounds__(TPB) void hist_kernel(const int* __restrict__ col,
                                                   int* __restrict__ counts,
                                                   int E, int nblk, int nbuck) {
    __shared__ int hist[512];
    int t = threadIdx.x;
    for (int i = t; i < nbuck; i += TPB) hist[i] = 0;
    __syncthreads();
    int e0 = blockIdx.x * CHUNK;
    for (int i = t; i < CHUNK; i += TPB) {
        int e = e0 + i;
        if (e < E) atomicAdd(&hist[col[e] >> BK_SHIFT], 1);   // LDS atomic
    }
    __syncthreads();
    for (int i = t; i < nbuck; i += TPB) counts[i * nblk + blockIdx.x] = hist[i];
}

// generic exclusive scan, 3 kernels
__global__ __launch_bounds__(TPB) void scan1_kernel(const int* __restrict__ in,
                                                    int* __restrict__ out,
                                                    int* __restrict__ bsum, int L) {
    __shared__ int s[TPB];
    int t = threadIdx.x;
    int i = blockIdx.x * TPB + t;
    int d = (i < L) ? in[i] : 0;
    s[t] = d; __syncthreads();
    for (int off = 1; off < TPB; off <<= 1) {
        int v = (t >= off) ? s[t - off] : 0;
        __syncthreads();
        s[t] += v;
        __syncthreads();
    }
    if (i < L) out[i] = s[t] - d;
    if (t == TPB - 1) bsum[blockIdx.x] = s[t];
}

// single-block exclusive scan of up to 2048 block sums (2 elems/thread)
__global__ __launch_bounds__(1024) void scan2_kernel(int* __restrict__ bsum, int nb) {
    __shared__ int s[1024];
    int t = threadIdx.x;
    int i0 = t * 2, i1 = t * 2 + 1;
    int v0 = (i0 < nb) ? bsum[i0] : 0;
    int v1 = (i1 < nb) ? bsum[i1] : 0;
    int pv = v0 + v1;
    s[t] = pv; __syncthreads();
    for (int off = 1; off < 1024; off <<= 1) {
        int u = (t >= off) ? s[t - off] : 0;
        __syncthreads();
        s[t] += u;
        __syncthreads();
    }
    int exc = s[t] - pv;
    if (i0 < nb) bsum[i0] = exc;
    if (i1 < nb) bsum[i1] = exc + v0;
}

__global__ __launch_bounds__(TPB) void scan3g_kernel(int* __restrict__ out,
                                                     const int* __restrict__ bsum, int L) {
    int i = blockIdx.x * TPB + threadIdx.x;
    if (i < L) out[i] += bsum[blockIdx.x];
}

// S1c ∥ gemm, block-interleaved 1:1.  Scatter: bucketed[pos]=(local_col<<18)|row.
// Gemm: per-thread x row, W1 in LDS, 16 accumulators (latency hidden by
// co-resident scatter waves; R7 showed LDS-tiling x regresses).
__global__ __launch_bounds__(TPB) void s1c_gemm_kernel(
        const int* __restrict__ row, const int* __restrict__ col,
        const int* __restrict__ cbase, int E, int nblk, int nbuck,
        int* __restrict__ bucketed,
        const float* __restrict__ x, const float* __restrict__ W1,
        float* __restrict__ h1, int N, int nbg) {
    __shared__ int cur[NPB];
    __shared__ float w1s[128 * 16];
    int b = (int)blockIdx.x, t = threadIdx.x;
    int M = min(nblk, nbg);
    int role, id;
    if (b < 2 * M) { role = b & 1; id = b >> 1; }
    else           { role = (nblk > nbg) ? 0 : 1; id = b - M; }

    if (role == 0) {                         // scatter to bucket-major
        for (int i = t; i < nbuck; i += TPB) cur[i] = cbase[i * nblk + id];
        __syncthreads();
        int e0 = id * CHUNK;
        for (int i = t; i < CHUNK; i += TPB) {
            int e = e0 + i;
            if (e < E) {
                int c = col[e];
                int pos = atomicAdd(&cur[c >> BK_SHIFT], 1);   // LDS atomic
                bucketed[pos] = ((c & (NPB - 1)) << 18) | row[e];
            }
        }
        return;
    }
    // gemm: h1[n] = x[n] @ W1, one thread per node, W1 in LDS
    for (int i = t; i < 128 * 16; i += TPB) w1s[i] = W1[i];
    __syncthreads();
    int n = id * TPB + t;
    if (n >= N) return;
    const float4* xr = (const float4*)(x + (size_t)n * 128);
    float acc[16];
#pragma unroll
    for (int k = 0; k < 16; ++k) acc[k] = 0.f;
#pragma unroll 1
    for (int g = 0; g < 8; ++g) {
        float4 v0 = xr[g * 4 + 0], v1 = xr[g * 4 + 1];
        float4 v2 = xr[g * 4 + 2], v3 = xr[g * 4 + 3];
        float xv[16] = {v0.x, v0.y, v0.z, v0.w, v1.x, v1.y, v1.z, v1.w,
                        v2.x, v2.y, v2.z, v2.w, v3.x, v3.y, v3.z, v3.w};
#pragma unroll
        for (int cc = 0; cc < 16; ++cc) {
            const float4* w4 = (const float4*)&w1s[(g * 16 + cc) * 16];
            float4 wa = w4[0], wb = w4[1], wc = w4[2], wd = w4[3];
            float xc = xv[cc];
            acc[0]  = fmaf(xc, wa.x, acc[0]);  acc[1]  = fmaf(xc, wa.y, acc[1]);
            acc[2]  = fmaf(xc, wa.z, acc[2]);  acc[3]  = fmaf(xc, wa.w, acc[3]);
            acc[4]  = fmaf(xc, wb.x, acc[4]);  acc[5]  = fmaf(xc, wb.y, acc[5]);
            acc[6]  = fmaf(xc, wb.z, acc[6]);  acc[7]  = fmaf(xc, wb.w, acc[7]);
            acc[8]  = fmaf(xc, wc.x, acc[8]);  acc[9]  = fmaf(xc, wc.y, acc[9]);
            acc[10] = fmaf(xc, wc.z, acc[10]); acc[11] = fmaf(xc, wc.w, acc[11]);
            acc[12] = fmaf(xc, wd.x, acc[12]); acc[13] = fmaf(xc, wd.y, acc[13]);
            acc[14] = fmaf(xc, wd.z, acc[14]); acc[15] = fmaf(xc, wd.w, acc[15]);
        }
    }
    float4* o = (float4*)(h1 + (size_t)n * 16);
    o[0] = make_float4(acc[0], acc[1], acc[2], acc[3]);
    o[1] = make_float4(acc[4], acc[5], acc[6], acc[7]);
    o[2] = make_float4(acc[8], acc[9], acc[10], acc[11]);
    o[3] = make_float4(acc[12], acc[13], acc[14], acc[15]);
}

// S2: one block per 512-node bucket: counting sort, emit csr/offs/dinv,
// h1p = bf16(dinv*h1).
__global__ __launch_bounds__(TPB) void sort_kernel(
        const int* __restrict__ bucketed, const int* __restrict__ cbase,
        int E, int nblk, int nbuck,
        int* __restrict__ csr, int* __restrict__ offs, float* __restrict__ dinv,
        const float* __restrict__ h1, unsigned short* __restrict__ h1p, int N) {
    __shared__ int lhist[NPB];
    __shared__ int part[TPB];
    __shared__ float sdinv[NPB];
    int bk = blockIdx.x, t = threadIdx.x;
    int n0 = bk << BK_SHIFT;
    int n1 = min(n0 + NPB, N);
    int e0 = cbase[bk * nblk];
    int e1 = (bk + 1 < nbuck) ? cbase[(bk + 1) * nblk] : E;

    lhist[t] = 0; lhist[t + TPB] = 0;
    __syncthreads();
    for (int i = e0 + t; i < e1; i += TPB)
        atomicAdd(&lhist[bucketed[i] >> 18], 1);               // LDS atomic
    __syncthreads();

    int base = t * 2;
    int c0 = lhist[base], c1 = lhist[base + 1];
    int s = c0 + c1;
    part[t] = s;
    __syncthreads();
    for (int off = 1; off < TPB; off <<= 1) {
        int v = (t >= off) ? part[t - off] : 0;
        __syncthreads();
        part[t] += v;
        __syncthreads();
    }
    int o0 = e0 + part[t] - s;
    int o1 = o0 + c0;
    lhist[base] = o0; lhist[base + 1] = o1;
    sdinv[base]     = rsqrtf((float)c0 + 1.0f);
    sdinv[base + 1] = rsqrtf((float)c1 + 1.0f);
    int n = n0 + base;
    if (n + 0 < N) { offs[n + 0] = o0; dinv[n + 0] = sdinv[base]; }
    if (n + 1 < N) { offs[n + 1] = o1; dinv[n + 1] = sdinv[base + 1]; }
    __syncthreads();

    for (int i = e0 + t; i < e1; i += TPB) {
        int v = bucketed[i];
        int pos = atomicAdd(&lhist[v >> 18], 1);               // LDS atomic
        csr[pos] = v & 0x3FFFF;
    }
    int nq = (n1 - n0) * 4;
    for (int i = t; i < nq; i += TPB) {
        float dv = sdinv[i >> 2];
        float4 v = ((const float4*)h1)[(size_t)n0 * 4 + i];
        ((ushort4*)h1p)[(size_t)n0 * 4 + i] =
            make_ushort4(f2bf(v.x * dv), f2bf(v.y * dv), f2bf(v.z * dv), f2bf(v.w * dv));
    }
    if (bk == 0 && t == 0) offs[N] = E;
}

// gather1: 16 lanes/node, 32 edges in flight per iteration.
// h2p[c] = bf16( dinv[c]*relu( dinv[c]*(sum h1p[src] + h1p[c]) + b1 ) )
__global__ __launch_bounds__(TPB) void gather1_kernel(const int* __restrict__ csr,
                                                      const int* __restrict__ offs,
                                                      const unsigned short* __restrict__ h1p,
                                                      const float* __restrict__ dinv,
                                                      const float* __restrict__ b1,
                                                      unsigned short* __restrict__ h2p, int N) {
    int t = threadIdx.x;
    int c = blockIdx.x * 16 + (t >> 4);
    int k = t & 15;
    if (c >= N) return;
    int p0 = offs[c], p1 = offs[c + 1];
    float acc = 0.f;
    for (int p = p0; p < p1; p += 32) {
        int s0 = csr[min(p + k, p1 - 1)];
        int s1 = csr[min(p + 16 + k, p1 - 1)];
        int rem = p1 - p;
        float v[32];
#pragma unroll
        for (int j = 0; j < 16; ++j) {
            int sj = __shfl(s0, j, 16);
            v[j] = bf2f(h1p[(size_t)sj * 16 + k]);
        }
#pragma unroll
        for (int j = 0; j < 16; ++j) {
            int sj = __shfl(s1, j, 16);
            v[16 + j] = bf2f(h1p[(size_t)sj * 16 + k]);
        }
#pragma unroll
        for (int j = 0; j < 32; ++j) acc += (j < rem) ? v[j] : 0.f;
    }
    float dc = dinv[c];
    float self = bf2f(h1p[(size_t)c * 16 + k]);
    float a = fmaf(dc, acc + self, b1[k]);
    h2p[(size_t)c * 16 + k] = f2bf(dc * fmaxf(a, 0.f));
}

// gather2: a2[c] = dinv[c]*(sum h2p[src] + h2p[c])   (fp32 out)
__global__ __launch_bounds__(TPB) void gather2_kernel(const int* __restrict__ csr,
                                                      const int* __restrict__ offs,
                                                      const unsigned short* __restrict__ h2p,
                                                      const float* __restrict__ dinv,
                                                      float* __restrict__ a2, int N) {
    int t = threadIdx.x;
    int c = blockIdx.x * 16 + (t >> 4);
    int k = t & 15;
    if (c >= N) return;
    int p0 = offs[c], p1 = offs[c + 1];
    float acc = 0.f;
    for (int p = p0; p < p1; p += 32) {
        int s0 = csr[min(p + k, p1 - 1)];
        int s1 = csr[min(p + 16 + k, p1 - 1)];
        int rem = p1 - p;
        float v[32];
#pragma unroll
        for (int j = 0; j < 16; ++j) {
            int sj = __shfl(s0, j, 16);
            v[j] = bf2f(h2p[(size_t)sj * 16 + k]);
        }
#pragma unroll
        for (int j = 0; j < 16; ++j) {
            int sj = __shfl(s1, j, 16);
            v[16 + j] = bf2f(h2p[(size_t)sj * 16 + k]);
        }
#pragma unroll
        for (int j = 0; j < 32; ++j) acc += (j < rem) ? v[j] : 0.f;
    }
    float self = bf2f(h2p[(size_t)c * 16 + k]);
    a2[(size_t)c * 16 + k] = dinv[c] * (acc + self);
}

// final: out[g] += a2[n]@W2 + b2, pooled over sorted batch; 64 nodes per wave
__global__ __launch_bounds__(TPB) void final_kernel(const float* __restrict__ a2,
                                                    const float* __restrict__ W2,
                                                    const float* __restrict__ b2,
                                                    const int* __restrict__ batch,
                                                    float* __restrict__ out, int N) {
    __shared__ float w2s[16 * 64];
    int t = threadIdx.x;
    for (int i = t; i < 16 * 64; i += TPB) w2s[i] = W2[i];
    __syncthreads();

    int wave = t >> 6, lane = t & 63;
    int n0 = blockIdx.x * 256 + wave * 64;
    float b2k = b2[lane];
    int g_cur = -1;
    float acc = 0.f;
    for (int i = 0; i < 64; ++i) {
        int n = n0 + i;
        if (n >= N) break;
        const float* ar = a2 + (size_t)n * 16;
        float val = b2k;
#pragma unroll
        for (int j = 0; j < 16; ++j) val = fmaf(ar[j], w2s[j * 64 + lane], val);
        int g = batch[n];
        if (g != g_cur) {
            if (g_cur >= 0) atomicAdd(&out[(size_t)g_cur * 64 + lane], acc);
            acc = 0.f;
            g_cur = g;
        }
        acc += val;
    }
    if (g_cur >= 0) atomicAdd(&out[(size_t)g_cur * 64 + lane], acc);
}

static inline size_t align64(size_t v) { return (v + 63) & ~(size_t)63; }

extern "C" void kernel_launch(void* const* d_in, const int* in_sizes, int n_in,
                              void* d_out, int out_size, void* d_ws, size_t ws_size,
                              hipStream_t stream) {
    const float* x     = (const float*)d_in[0];
    const int*   ei    = (const int*)d_in[1];
    const int*   batch = (const int*)d_in[2];
    const float* W1    = (const float*)d_in[3];
    const float* b1    = (const float*)d_in[4];
    const float* W2    = (const float*)d_in[5];
    const float* b2    = (const float*)d_in[6];

    const int N = in_sizes[0] / 128;
    const int E = in_sizes[1] / 2;
    const int* row = ei;        // edge_index[0]
    const int* col = ei + E;    // edge_index[1]

    const int NBLK  = (E + CHUNK - 1) / CHUNK;       // 782
    const int NBUCK = (N + NPB - 1) / NPB;           // 391 (<=512)
    const int L     = NBUCK * NBLK;                  // 305762
    const int NBS   = (L + TPB - 1) / TPB;           // 1195 (<=2048 for scan2)
    const int NBG   = (N + TPB - 1) / TPB;           // 782

    char* p = (char*)d_ws;
    int*            counts   = (int*)p;            p += align64((size_t)L * 4);
    int*            bsum     = (int*)p;            p += align64(2048 * 4);
    int*            bucketed = (int*)p;            p += align64((size_t)E * 4);
    int*            csr      = (int*)p;            p += align64((size_t)E * 4);
    int*            offs     = (int*)p;            p += align64((size_t)(N + 1) * 4);
    float*          dinv     = (float*)p;          p += align64((size_t)N * 4);
    float*          h1       = (float*)p;          p += align64((size_t)N * 16 * 4);
    unsigned short* h1p      = (unsigned short*)p; p += align64((size_t)N * 16 * 2);
    unsigned short* h2p      = (unsigned short*)p; p += align64((size_t)N * 16 * 2);
    float*          a2       = h1;                 // h1 dead after sort_kernel
    float*          out      = (float*)d_out;

    hipMemsetAsync(out, 0, (size_t)out_size * sizeof(float), stream);

    hist_kernel<<<NBLK, TPB, 0, stream>>>(col, counts, E, NBLK, NBUCK);
    scan1_kernel<<<NBS, TPB, 0, stream>>>(counts, counts, bsum, L);
    scan2_kernel<<<1, 1024, 0, stream>>>(bsum, NBS);
    scan3g_kernel<<<NBS, TPB, 0, stream>>>(counts, bsum, L);
    s1c_gemm_kernel<<<NBLK + NBG, TPB, 0, stream>>>(row, col, counts, E, NBLK, NBUCK,
                                                    bucketed, x, W1, h1, N, NBG);
    sort_kernel<<<NBUCK, TPB, 0, stream>>>(bucketed, counts, E, NBLK, NBUCK,
                                           csr, offs, dinv, h1, h1p, N);
    gather1_kernel<<<(N + 15) / 16, TPB, 0, stream>>>(csr, offs, h1p, dinv, b1, h2p, N);
    gather2_kernel<<<(N + 15) / 16, TPB, 0, stream>>>(csr, offs, h2p, dinv, a2, N);
    final_kernel<<<(N + 255) / 256, TPB, 0, stream>>>(a2, W2, b2, batch, out, N);
}

// Round 10
// 358.992 us; speedup vs baseline: 1.2973x; 1.0433x over previous
//
#include <hip/hip_runtime.h>

// 2-layer GCN, CSR-gather, bf16 payloads, zero global atomics.
//   hist(512-node buckets) -> scan1/scan2 -> [scatter ∥ gemm, 1:1] -> sort
//   -> gather1 -> gather2f (gather + W2 matmul + pooled output, fused).
// R9 lessons kept: 1:1 scatter/gemm interleave, 512-node buckets, packed
// 1-int bucket entries, 32-edges-in-flight gathers.
// R10: h1 stored bf16 (halves h1 traffic); scan3g folded into consumers
// (cbase = counts[f] + bsum[f>>8]); final fused into gather2 via LDS
// (a2 never materialized; block-level pooled atomics stay ~200K total).

#define TPB 256
#define CHUNK 4096          // edges per stage-1 block (1:1 with gemm blocks)
#define BK_SHIFT 9
#define NPB 512             // nodes per bucket = 1 << BK_SHIFT

__device__ __forceinline__ float bf2f(unsigned short u) {
    union { unsigned int i; float f; } v; v.i = ((unsigned int)u) << 16; return v.f;
}
__device__ __forceinline__ unsigned short f2bf(float f) {
    union { float f; unsigned int i; } v; v.f = f;
    unsigned int r = v.i + 0x7fff + ((v.i >> 16) & 1);   // RNE
    return (unsigned short)(r >> 16);
}

// S1a: counts[bk*nblk + blk] = #edges in block blk with col>>9 == bk
__global__ __launch_bounds__(TPB) void hist_kernel(const int* __restrict__ col,
                                                   int* __restrict__ counts,
                                                   int E, int nblk, int nbuck) {
    __shared__ int hist[512];
    int t = threadIdx.x;
    for (int i = t; i < nbuck; i += TPB) hist[i] = 0;
    __syncthreads();
    int e0 = blockIdx.x * CHUNK;
    for (int i = t; i < CHUNK; i += TPB) {
        int e = e0 + i;
        if (e < E) atomicAdd(&hist[col[e] >> BK_SHIFT], 1);   // LDS atomic
    }
    __syncthreads();
    for (int i = t; i < nbuck; i += TPB) counts[i * nblk + blockIdx.x] = hist[i];
}

// scan1: per-256-block exclusive scan (counts in place), bsum[b]=block total
__global__ __launch_bounds__(TPB) void scan1_kernel(const int* __restrict__ in,
                                                    int* __restrict__ out,
                                                    int* __restrict__ bsum, int L) {
    __shared__ int s[TPB];
    int t = threadIdx.x;
    int i = blockIdx.x * TPB + t;
    int d = (i < L) ? in[i] : 0;
    s[t] = d; __syncthreads();
    for (int off = 1; off < TPB; off <<= 1) {
        int v = (t >= off) ? s[t - off] : 0;
        __syncthreads();
        s[t] += v;
        __syncthreads();
    }
    if (i < L) out[i] = s[t] - d;
    if (t == TPB - 1) bsum[blockIdx.x] = s[t];
}

// scan2: single-block exclusive scan of up to 2048 block sums (2 elems/thread)
__global__ __launch_bounds__(1024) void scan2_kernel(int* __restrict__ bsum, int nb) {
    __shared__ int s[1024];
    int t = threadIdx.x;
    int i0 = t * 2, i1 = t * 2 + 1;
    int v0 = (i0 < nb) ? bsum[i0] : 0;
    int v1 = (i1 < nb) ? bsum[i1] : 0;
    int pv = v0 + v1;
    s[t] = pv; __syncthreads();
    for (int off = 1; off < 1024; off <<= 1) {
        int u = (t >= off) ? s[t - off] : 0;
        __syncthreads();
        s[t] += u;
        __syncthreads();
    }
    int exc = s[t] - pv;
    if (i0 < nb) bsum[i0] = exc;
    if (i1 < nb) bsum[i1] = exc + v0;
}

// cbase[f] = counts[f] + bsum[f>>8]   (scan3g folded into consumers)
__device__ __forceinline__ int cbase_at(const int* counts, const int* bsum, int f) {
    return counts[f] + bsum[f >> 8];
}

// S1c ∥ gemm, block-interleaved 1:1.  Scatter: bucketed[pos]=(local_col<<18)|row.
// Gemm: per-thread x row, W1 in LDS, 16 accumulators, h1 written bf16 unscaled.
__global__ __launch_bounds__(TPB) void s1c_gemm_kernel(
        const int* __restrict__ row, const int* __restrict__ col,
        const int* __restrict__ counts, const int* __restrict__ bsum,
        int E, int nblk, int nbuck,
        int* __restrict__ bucketed,
        const float* __restrict__ x, const float* __restrict__ W1,
        unsigned short* __restrict__ h1b, int N, int nbg) {
    __shared__ int cur[NPB];
    __shared__ float w1s[128 * 16];
    int b = (int)blockIdx.x, t = threadIdx.x;
    int M = min(nblk, nbg);
    int role, id;
    if (b < 2 * M) { role = b & 1; id = b >> 1; }
    else           { role = (nblk > nbg) ? 0 : 1; id = b - M; }

    if (role == 0) {                         // scatter to bucket-major
        for (int i = t; i < nbuck; i += TPB)
            cur[i] = cbase_at(counts, bsum, i * nblk + id);
        __syncthreads();
        int e0 = id * CHUNK;
        for (int i = t; i < CHUNK; i += TPB) {
            int e = e0 + i;
            if (e < E) {
                int c = col[e];
                int pos = atomicAdd(&cur[c >> BK_SHIFT], 1);   // LDS atomic
                bucketed[pos] = ((c & (NPB - 1)) << 18) | row[e];
            }
        }
        return;
    }
    // gemm: h1b[n] = bf16(x[n] @ W1), one thread per node, W1 in LDS
    for (int i = t; i < 128 * 16; i += TPB) w1s[i] = W1[i];
    __syncthreads();
    int n = id * TPB + t;
    if (n >= N) return;
    const float4* xr = (const float4*)(x + (size_t)n * 128);
    float acc[16];
#pragma unroll
    for (int k = 0; k < 16; ++k) acc[k] = 0.f;
#pragma unroll 1
    for (int g = 0; g < 8; ++g) {
        float4 v0 = xr[g * 4 + 0], v1 = xr[g * 4 + 1];
        float4 v2 = xr[g * 4 + 2], v3 = xr[g * 4 + 3];
        float xv[16] = {v0.x, v0.y, v0.z, v0.w, v1.x, v1.y, v1.z, v1.w,
                        v2.x, v2.y, v2.z, v2.w, v3.x, v3.y, v3.z, v3.w};
#pragma unroll
        for (int cc = 0; cc < 16; ++cc) {
            const float4* w4 = (const float4*)&w1s[(g * 16 + cc) * 16];
            float4 wa = w4[0], wb = w4[1], wc = w4[2], wd = w4[3];
            float xc = xv[cc];
            acc[0]  = fmaf(xc, wa.x, acc[0]);  acc[1]  = fmaf(xc, wa.y, acc[1]);
            acc[2]  = fmaf(xc, wa.z, acc[2]);  acc[3]  = fmaf(xc, wa.w, acc[3]);
            acc[4]  = fmaf(xc, wb.x, acc[4]);  acc[5]  = fmaf(xc, wb.y, acc[5]);
            acc[6]  = fmaf(xc, wb.z, acc[6]);  acc[7]  = fmaf(xc, wb.w, acc[7]);
            acc[8]  = fmaf(xc, wc.x, acc[8]);  acc[9]  = fmaf(xc, wc.y, acc[9]);
            acc[10] = fmaf(xc, wc.z, acc[10]); acc[11] = fmaf(xc, wc.w, acc[11]);
            acc[12] = fmaf(xc, wd.x, acc[12]); acc[13] = fmaf(xc, wd.y, acc[13]);
            acc[14] = fmaf(xc, wd.z, acc[14]); acc[15] = fmaf(xc, wd.w, acc[15]);
        }
    }
    unsigned int u[8];
#pragma unroll
    for (int j = 0; j < 8; ++j)
        u[j] = (unsigned int)f2bf(acc[2 * j]) | ((unsigned int)f2bf(acc[2 * j + 1]) << 16);
    uint4* o = (uint4*)(h1b + (size_t)n * 16);
    o[0] = make_uint4(u[0], u[1], u[2], u[3]);
    o[1] = make_uint4(u[4], u[5], u[6], u[7]);
}

// S2: one block per 512-node bucket: counting sort, emit csr/offs/dinv,
// h1p = bf16(dinv * h1b).
__global__ __launch_bounds__(TPB) void sort_kernel(
        const int* __restrict__ bucketed,
        const int* __restrict__ counts, const int* __restrict__ bsum,
        int E, int nblk, int nbuck,
        int* __restrict__ csr, int* __restrict__ offs, float* __restrict__ dinv,
        const unsigned short* __restrict__ h1b, unsigned short* __restrict__ h1p, int N) {
    __shared__ int lhist[NPB];
    __shared__ int part[TPB];
    __shared__ float sdinv[NPB];
    int bk = blockIdx.x, t = threadIdx.x;
    int n0 = bk << BK_SHIFT;
    int n1 = min(n0 + NPB, N);
    int e0 = cbase_at(counts, bsum, bk * nblk);
    int e1 = (bk + 1 < nbuck) ? cbase_at(counts, bsum, (bk + 1) * nblk) : E;

    lhist[t] = 0; lhist[t + TPB] = 0;
    __syncthreads();
    for (int i = e0 + t; i < e1; i += TPB)
        atomicAdd(&lhist[bucketed[i] >> 18], 1);               // LDS atomic
    __syncthreads();

    int base = t * 2;
    int c0 = lhist[base], c1 = lhist[base + 1];
    int s = c0 + c1;
    part[t] = s;
    __syncthreads();
    for (int off = 1; off < TPB; off <<= 1) {
        int v = (t >= off) ? part[t - off] : 0;
        __syncthreads();
        part[t] += v;
        __syncthreads();
    }
    int o0 = e0 + part[t] - s;
    int o1 = o0 + c0;
    lhist[base] = o0; lhist[base + 1] = o1;
    sdinv[base]     = rsqrtf((float)c0 + 1.0f);
    sdinv[base + 1] = rsqrtf((float)c1 + 1.0f);
    int n = n0 + base;
    if (n + 0 < N) { offs[n + 0] = o0; dinv[n + 0] = sdinv[base]; }
    if (n + 1 < N) { offs[n + 1] = o1; dinv[n + 1] = sdinv[base + 1]; }
    __syncthreads();

    for (int i = e0 + t; i < e1; i += TPB) {
        int v = bucketed[i];
        int pos = atomicAdd(&lhist[v >> 18], 1);               // LDS atomic
        csr[pos] = v & 0x3FFFF;
    }
    int nq = (n1 - n0) * 4;                  // one quad (4 feats) per i
    for (int i = t; i < nq; i += TPB) {
        float dv = sdinv[i >> 2];
        uint2 u = ((const uint2*)h1b)[(size_t)n0 * 4 + i];
        float f0 = bf2f((unsigned short)(u.x & 0xffff));
        float f1 = bf2f((unsigned short)(u.x >> 16));
        float f2 = bf2f((unsigned short)(u.y & 0xffff));
        float f3 = bf2f((unsigned short)(u.y >> 16));
        ((ushort4*)h1p)[(size_t)n0 * 4 + i] =
            make_ushort4(f2bf(f0 * dv), f2bf(f1 * dv), f2bf(f2 * dv), f2bf(f3 * dv));
    }
    if (bk == 0 && t == 0) offs[N] = E;
}

// gather1: 16 lanes/node, 32 edges in flight per iteration.
// h2p[c] = bf16( dinv[c]*relu( dinv[c]*(sum h1p[src] + h1p[c]) + b1 ) )
__global__ __launch_bounds__(TPB) void gather1_kernel(const int* __restrict__ csr,
                                                      const int* __restrict__ offs,
                                                      const unsigned short* __restrict__ h1p,
                                                      const float* __restrict__ dinv,
                                                      const float* __restrict__ b1,
                                                      unsigned short* __restrict__ h2p, int N) {
    int t = threadIdx.x;
    int c = blockIdx.x * 16 + (t >> 4);
    int k = t & 15;
    if (c >= N) return;
    int p0 = offs[c], p1 = offs[c + 1];
    float acc = 0.f;
    for (int p = p0; p < p1; p += 32) {
        int s0 = csr[min(p + k, p1 - 1)];
        int s1 = csr[min(p + 16 + k, p1 - 1)];
        int rem = p1 - p;
        float v[32];
#pragma unroll
        for (int j = 0; j < 16; ++j) {
            int sj = __shfl(s0, j, 16);
            v[j] = bf2f(h1p[(size_t)sj * 16 + k]);
        }
#pragma unroll
        for (int j = 0; j < 16; ++j) {
            int sj = __shfl(s1, j, 16);
            v[16 + j] = bf2f(h1p[(size_t)sj * 16 + k]);
        }
#pragma unroll
        for (int j = 0; j < 32; ++j) acc += (j < rem) ? v[j] : 0.f;
    }
    float dc = dinv[c];
    float self = bf2f(h1p[(size_t)c * 16 + k]);
    float a = fmaf(dc, acc + self, b1[k]);
    h2p[(size_t)c * 16 + k] = f2bf(dc * fmaxf(a, 0.f));
}

// gather2f: fused gather2 + W2 matmul + sorted-batch pooling.  Block = 64 nodes.
// Phase 1: 16 groups x 16 lanes gather a2 rows (4 nodes/group) into LDS asT.
// Phase 2: wave w: 64 lanes = output dims, 16 nodes from asT, W2 slice in regs,
//          run-accumulate; uniform-batch blocks pool in LDS, flush 64 atomics.
__global__ __launch_bounds__(TPB) void gather2f_kernel(
        const int* __restrict__ csr, const int* __restrict__ offs,
        const unsigned short* __restrict__ h2p, const float* __restrict__ dinv,
        const float* __restrict__ W2, const float* __restrict__ b2,
        const int* __restrict__ batch, float* __restrict__ out, int N) {
    __shared__ float w2s[16 * 64];
    __shared__ float asT[64 * 17];
    __shared__ float pool[64];
    int t = threadIdx.x;
    for (int i = t; i < 16 * 64; i += TPB) w2s[i] = W2[i];
    if (t < 64) pool[t] = 0.f;

    int n0 = blockIdx.x * 64;
    int nLast = min(n0 + 63, N - 1);
    int g0 = batch[n0];
    bool uniform = (batch[nLast] == g0);     // batch sorted

    // phase 1: gather (4 nodes per 16-lane group)
    int grp = t >> 4, k = t & 15;
#pragma unroll 1
    for (int it = 0; it < 4; ++it) {
        int m = grp * 4 + it;
        int c = n0 + m;
        if (c < N) {
            int p0 = offs[c], p1 = offs[c + 1];
            float acc = 0.f;
            for (int p = p0; p < p1; p += 32) {
                int s0 = csr[min(p + k, p1 - 1)];
                int s1 = csr[min(p + 16 + k, p1 - 1)];
                int rem = p1 - p;
                float v[32];
#pragma unroll
                for (int j = 0; j < 16; ++j) {
                    int sj = __shfl(s0, j, 16);
                    v[j] = bf2f(h2p[(size_t)sj * 16 + k]);
                }
#pragma unroll
                for (int j = 0; j < 16; ++j) {
                    int sj = __shfl(s1, j, 16);
                    v[16 + j] = bf2f(h2p[(size_t)sj * 16 + k]);
                }
#pragma unroll
                for (int j = 0; j < 32; ++j) acc += (j < rem) ? v[j] : 0.f;
            }
            float self = bf2f(h2p[(size_t)c * 16 + k]);
            asT[m * 17 + k] = dinv[c] * (acc + self);
        }
    }
    __syncthreads();

    // phase 2: wave w covers nodes n0+16w .. n0+16w+15
    int wave = t >> 6, j = t & 63;
    float w2reg[16];
#pragma unroll
    for (int kk = 0; kk < 16; ++kk) w2reg[kk] = w2s[kk * 64 + j];
    float b2j = b2[j];
    float val = 0.f;
    int g_cur = -1;
#pragma unroll 1
    for (int mi = 0; mi < 16; ++mi) {
        int m = wave * 16 + mi;
        int c = n0 + m;
        if (c >= N) break;
        const float* ar = &asT[m * 17];
        float y = b2j;
#pragma unroll
        for (int kk = 0; kk < 16; ++kk) y = fmaf(ar[kk], w2reg[kk], y);
        if (uniform) {
            val += y;
        } else {
            int g = batch[c];
            if (g != g_cur) {
                if (g_cur >= 0) atomicAdd(&out[(size_t)g_cur * 64 + j], val);
                val = 0.f;
                g_cur = g;
            }
            val += y;
        }
    }
    if (uniform) {
        atomicAdd(&pool[j], val);            // LDS, 4-way per address
        __syncthreads();
        if (t < 64) atomicAdd(&out[(size_t)g0 * 64 + t], pool[t]);
    } else {
        if (g_cur >= 0) atomicAdd(&out[(size_t)g_cur * 64 + j], val);
    }
}

static inline size_t align64(size_t v) { return (v + 63) & ~(size_t)63; }

extern "C" void kernel_launch(void* const* d_in, const int* in_sizes, int n_in,
                              void* d_out, int out_size, void* d_ws, size_t ws_size,
                              hipStream_t stream) {
    const float* x     = (const float*)d_in[0];
    const int*   ei    = (const int*)d_in[1];
    const int*   batch = (const int*)d_in[2];
    const float* W1    = (const float*)d_in[3];
    const float* b1    = (const float*)d_in[4];
    const float* W2    = (const float*)d_in[5];
    const float* b2    = (const float*)d_in[6];

    const int N = in_sizes[0] / 128;
    const int E = in_sizes[1] / 2;
    const int* row = ei;        // edge_index[0]
    const int* col = ei + E;    // edge_index[1]

    const int NBLK  = (E + CHUNK - 1) / CHUNK;       // 782
    const int NBUCK = (N + NPB - 1) / NPB;           // 391 (<=512)
    const int L     = NBUCK * NBLK;                  // 305762
    const int NBS   = (L + TPB - 1) / TPB;           // 1195 (<=2048 for scan2)
    const int NBG   = (N + TPB - 1) / TPB;           // 782

    char* p = (char*)d_ws;
    int*            counts   = (int*)p;            p += align64((size_t)L * 4);
    int*            bsum     = (int*)p;            p += align64(2048 * 4);
    int*            bucketed = (int*)p;            p += align64((size_t)E * 4);
    int*            csr      = (int*)p;            p += align64((size_t)E * 4);
    int*            offs     = (int*)p;            p += align64((size_t)(N + 1) * 4);
    float*          dinv     = (float*)p;          p += align64((size_t)N * 4);
    unsigned short* h1b      = (unsigned short*)p; p += align64((size_t)N * 16 * 2);
    unsigned short* h1p      = (unsigned short*)p; p += align64((size_t)N * 16 * 2);
    unsigned short* h2p      = (unsigned short*)p; p += align64((size_t)N * 16 * 2);
    float*          out      = (float*)d_out;

    hipMemsetAsync(out, 0, (size_t)out_size * sizeof(float), stream);

    hist_kernel<<<NBLK, TPB, 0, stream>>>(col, counts, E, NBLK, NBUCK);
    scan1_kernel<<<NBS, TPB, 0, stream>>>(counts, counts, bsum, L);
    scan2_kernel<<<1, 1024, 0, stream>>>(bsum, NBS);
    s1c_gemm_kernel<<<NBLK + NBG, TPB, 0, stream>>>(row, col, counts, bsum,
                                                    E, NBLK, NBUCK,
                                                    bucketed, x, W1, h1b, N, NBG);
    sort_kernel<<<NBUCK, TPB, 0, stream>>>(bucketed, counts, bsum, E, NBLK, NBUCK,
                                           csr, offs, dinv, h1b, h1p, N);
    gather1_kernel<<<(N + 15) / 16, TPB, 0, stream>>>(csr, offs, h1p, dinv, b1, h2p, N);
    gather2f_kernel<<<(N + 63) / 64, TPB, 0, stream>>>(csr, offs, h2p, dinv,
                                                       W2, b2, batch, out, N);
}

// Round 11
// 354.585 us; speedup vs baseline: 1.3135x; 1.0124x over previous
//
#include <hip/hip_runtime.h>

// 2-layer GCN, CSR-gather, bf16 payloads, zero global atomics.
//   hist(512-node buckets) -> scan1/scan2 -> [scatter ∥ gemm, 1:1] -> sort
//   -> gather1 -> gather2f (gather + W2 matmul + pooled output, fused).
// Kept: 1:1 scatter/gemm interleave (R9), 512-node buckets, packed 1-int
// bucket entries, bf16 h1 (R10), scan3g folded into consumers (R10),
// final fused into gather2 (R10).
// R11: gemm g-loop unrolled x2 (8 x-loads in flight; gemm was latency-starved
// at 4); gathers load uint (2 bf16 feats) -> half the scattered-load instrs,
// 2 edges per load instruction per 16-lane group, cross-half shfl_xor reduce.

#define TPB 256
#define CHUNK 4096          // edges per stage-1 block (1:1 with gemm blocks)
#define BK_SHIFT 9
#define NPB 512             // nodes per bucket = 1 << BK_SHIFT

__device__ __forceinline__ float bf2f(unsigned short u) {
    union { unsigned int i; float f; } v; v.i = ((unsigned int)u) << 16; return v.f;
}
__device__ __forceinline__ unsigned short f2bf(float f) {
    union { float f; unsigned int i; } v; v.f = f;
    unsigned int r = v.i + 0x7fff + ((v.i >> 16) & 1);   // RNE
    return (unsigned short)(r >> 16);
}

// S1a: counts[bk*nblk + blk] = #edges in block blk with col>>9 == bk
__global__ __launch_bounds__(TPB) void hist_kernel(const int* __restrict__ col,
                                                   int* __restrict__ counts,
                                                   int E, int nblk, int nbuck) {
    __shared__ int hist[512];
    int t = threadIdx.x;
    for (int i = t; i < nbuck; i += TPB) hist[i] = 0;
    __syncthreads();
    int e0 = blockIdx.x * CHUNK;
    for (int i = t; i < CHUNK; i += TPB) {
        int e = e0 + i;
        if (e < E) atomicAdd(&hist[col[e] >> BK_SHIFT], 1);   // LDS atomic
    }
    __syncthreads();
    for (int i = t; i < nbuck; i += TPB) counts[i * nblk + blockIdx.x] = hist[i];
}

// scan1: per-256-block exclusive scan (counts in place), bsum[b]=block total
__global__ __launch_bounds__(TPB) void scan1_kernel(const int* __restrict__ in,
                                                    int* __restrict__ out,
                                                    int* __restrict__ bsum, int L) {
    __shared__ int s[TPB];
    int t = threadIdx.x;
    int i = blockIdx.x * TPB + t;
    int d = (i < L) ? in[i] : 0;
    s[t] = d; __syncthreads();
    for (int off = 1; off < TPB; off <<= 1) {
        int v = (t >= off) ? s[t - off] : 0;
        __syncthreads();
        s[t] += v;
        __syncthreads();
    }
    if (i < L) out[i] = s[t] - d;
    if (t == TPB - 1) bsum[blockIdx.x] = s[t];
}

// scan2: single-block exclusive scan of up to 2048 block sums (2 elems/thread)
__global__ __launch_bounds__(1024) void scan2_kernel(int* __restrict__ bsum, int nb) {
    __shared__ int s[1024];
    int t = threadIdx.x;
    int i0 = t * 2, i1 = t * 2 + 1;
    int v0 = (i0 < nb) ? bsum[i0] : 0;
    int v1 = (i1 < nb) ? bsum[i1] : 0;
    int pv = v0 + v1;
    s[t] = pv; __syncthreads();
    for (int off = 1; off < 1024; off <<= 1) {
        int u = (t >= off) ? s[t - off] : 0;
        __syncthreads();
        s[t] += u;
        __syncthreads();
    }
    int exc = s[t] - pv;
    if (i0 < nb) bsum[i0] = exc;
    if (i1 < nb) bsum[i1] = exc + v0;
}

// cbase[f] = counts[f] + bsum[f>>8]   (scan3g folded into consumers)
__device__ __forceinline__ int cbase_at(const int* counts, const int* bsum, int f) {
    return counts[f] + bsum[f >> 8];
}

// S1c ∥ gemm, block-interleaved 1:1.  Scatter: bucketed[pos]=(local_col<<18)|row.
// Gemm: per-thread x row, W1 in LDS, 16 accumulators, g-loop unrolled x2
// (8 float4 loads in flight), h1 written bf16 unscaled.
__global__ __launch_bounds__(TPB) void s1c_gemm_kernel(
        const int* __restrict__ row, const int* __restrict__ col,
        const int* __restrict__ counts, const int* __restrict__ bsum,
        int E, int nblk, int nbuck,
        int* __restrict__ bucketed,
        const float* __restrict__ x, const float* __restrict__ W1,
        unsigned short* __restrict__ h1b, int N, int nbg) {
    __shared__ int cur[NPB];
    __shared__ float w1s[128 * 16];
    int b = (int)blockIdx.x, t = threadIdx.x;
    int M = min(nblk, nbg);
    int role, id;
    if (b < 2 * M) { role = b & 1; id = b >> 1; }
    else           { role = (nblk > nbg) ? 0 : 1; id = b - M; }

    if (role == 0) {                         // scatter to bucket-major
        for (int i = t; i < nbuck; i += TPB)
            cur[i] = cbase_at(counts, bsum, i * nblk + id);
        __syncthreads();
        int e0 = id * CHUNK;
        for (int i = t; i < CHUNK; i += TPB) {
            int e = e0 + i;
            if (e < E) {
                int c = col[e];
                int pos = atomicAdd(&cur[c >> BK_SHIFT], 1);   // LDS atomic
                bucketed[pos] = ((c & (NPB - 1)) << 18) | row[e];
            }
        }
        return;
    }
    // gemm: h1b[n] = bf16(x[n] @ W1), one thread per node, W1 in LDS
    for (int i = t; i < 128 * 16; i += TPB) w1s[i] = W1[i];
    __syncthreads();
    int n = id * TPB + t;
    if (n >= N) return;
    const float4* xr = (const float4*)(x + (size_t)n * 128);
    float acc[16];
#pragma unroll
    for (int k = 0; k < 16; ++k) acc[k] = 0.f;
#pragma unroll 1
    for (int g = 0; g < 8; g += 2) {         // two 16-col groups per window
        float4 vA0 = xr[g * 4 + 0], vA1 = xr[g * 4 + 1];
        float4 vA2 = xr[g * 4 + 2], vA3 = xr[g * 4 + 3];
        float4 vB0 = xr[g * 4 + 4], vB1 = xr[g * 4 + 5];
        float4 vB2 = xr[g * 4 + 6], vB3 = xr[g * 4 + 7];
        float xva[16] = {vA0.x, vA0.y, vA0.z, vA0.w, vA1.x, vA1.y, vA1.z, vA1.w,
                         vA2.x, vA2.y, vA2.z, vA2.w, vA3.x, vA3.y, vA3.z, vA3.w};
        float xvb[16] = {vB0.x, vB0.y, vB0.z, vB0.w, vB1.x, vB1.y, vB1.z, vB1.w,
                         vB2.x, vB2.y, vB2.z, vB2.w, vB3.x, vB3.y, vB3.z, vB3.w};
#pragma unroll
        for (int cc = 0; cc < 16; ++cc) {
            const float4* w4 = (const float4*)&w1s[(g * 16 + cc) * 16];
            float4 wa = w4[0], wb = w4[1], wc = w4[2], wd = w4[3];
            float xc = xva[cc];
            acc[0]  = fmaf(xc, wa.x, acc[0]);  acc[1]  = fmaf(xc, wa.y, acc[1]);
            acc[2]  = fmaf(xc, wa.z, acc[2]);  acc[3]  = fmaf(xc, wa.w, acc[3]);
            acc[4]  = fmaf(xc, wb.x, acc[4]);  acc[5]  = fmaf(xc, wb.y, acc[5]);
            acc[6]  = fmaf(xc, wb.z, acc[6]);  acc[7]  = fmaf(xc, wb.w, acc[7]);
            acc[8]  = fmaf(xc, wc.x, acc[8]);  acc[9]  = fmaf(xc, wc.y, acc[9]);
            acc[10] = fmaf(xc, wc.z, acc[10]); acc[11] = fmaf(xc, wc.w, acc[11]);
            acc[12] = fmaf(xc, wd.x, acc[12]); acc[13] = fmaf(xc, wd.y, acc[13]);
            acc[14] = fmaf(xc, wd.z, acc[14]); acc[15] = fmaf(xc, wd.w, acc[15]);
        }
#pragma unroll
        for (int cc = 0; cc < 16; ++cc) {
            const float4* w4 = (const float4*)&w1s[((g + 1) * 16 + cc) * 16];
            float4 wa = w4[0], wb = w4[1], wc = w4[2], wd = w4[3];
            float xc = xvb[cc];
            acc[0]  = fmaf(xc, wa.x, acc[0]);  acc[1]  = fmaf(xc, wa.y, acc[1]);
            acc[2]  = fmaf(xc, wa.z, acc[2]);  acc[3]  = fmaf(xc, wa.w, acc[3]);
            acc[4]  = fmaf(xc, wb.x, acc[4]);  acc[5]  = fmaf(xc, wb.y, acc[5]);
            acc[6]  = fmaf(xc, wb.z, acc[6]);  acc[7]  = fmaf(xc, wb.w, acc[7]);
            acc[8]  = fmaf(xc, wc.x, acc[8]);  acc[9]  = fmaf(xc, wc.y, acc[9]);
            acc[10] = fmaf(xc, wc.z, acc[10]); acc[11] = fmaf(xc, wc.w, acc[11]);
            acc[12] = fmaf(xc, wd.x, acc[12]); acc[13] = fmaf(xc, wd.y, acc[13]);
            acc[14] = fmaf(xc, wd.z, acc[14]); acc[15] = fmaf(xc, wd.w, acc[15]);
        }
    }
    unsigned int u[8];
#pragma unroll
    for (int j = 0; j < 8; ++j)
        u[j] = (unsigned int)f2bf(acc[2 * j]) | ((unsigned int)f2bf(acc[2 * j + 1]) << 16);
    uint4* o = (uint4*)(h1b + (size_t)n * 16);
    o[0] = make_uint4(u[0], u[1], u[2], u[3]);
    o[1] = make_uint4(u[4], u[5], u[6], u[7]);
}

// S2: one block per 512-node bucket: counting sort, emit csr/offs/dinv,
// h1p = bf16(dinv * h1b).
__global__ __launch_bounds__(TPB) void sort_kernel(
        const int* __restrict__ bucketed,
        const int* __restrict__ counts, const int* __restrict__ bsum,
        int E, int nblk, int nbuck,
        int* __restrict__ csr, int* __restrict__ offs, float* __restrict__ dinv,
        const unsigned short* __restrict__ h1b, unsigned short* __restrict__ h1p, int N) {
    __shared__ int lhist[NPB];
    __shared__ int part[TPB];
    __shared__ float sdinv[NPB];
    int bk = blockIdx.x, t = threadIdx.x;
    int n0 = bk << BK_SHIFT;
    int n1 = min(n0 + NPB, N);
    int e0 = cbase_at(counts, bsum, bk * nblk);
    int e1 = (bk + 1 < nbuck) ? cbase_at(counts, bsum, (bk + 1) * nblk) : E;

    lhist[t] = 0; lhist[t + TPB] = 0;
    __syncthreads();
    for (int i = e0 + t; i < e1; i += TPB)
        atomicAdd(&lhist[bucketed[i] >> 18], 1);               // LDS atomic
    __syncthreads();

    int base = t * 2;
    int c0 = lhist[base], c1 = lhist[base + 1];
    int s = c0 + c1;
    part[t] = s;
    __syncthreads();
    for (int off = 1; off < TPB; off <<= 1) {
        int v = (t >= off) ? part[t - off] : 0;
        __syncthreads();
        part[t] += v;
        __syncthreads();
    }
    int o0 = e0 + part[t] - s;
    int o1 = o0 + c0;
    lhist[base] = o0; lhist[base + 1] = o1;
    sdinv[base]     = rsqrtf((float)c0 + 1.0f);
    sdinv[base + 1] = rsqrtf((float)c1 + 1.0f);
    int n = n0 + base;
    if (n + 0 < N) { offs[n + 0] = o0; dinv[n + 0] = sdinv[base]; }
    if (n + 1 < N) { offs[n + 1] = o1; dinv[n + 1] = sdinv[base + 1]; }
    __syncthreads();

    for (int i = e0 + t; i < e1; i += TPB) {
        int v = bucketed[i];
        int pos = atomicAdd(&lhist[v >> 18], 1);               // LDS atomic
        csr[pos] = v & 0x3FFFF;
    }
    int nq = (n1 - n0) * 4;                  // one quad (4 feats) per i
    for (int i = t; i < nq; i += TPB) {
        float dv = sdinv[i >> 2];
        uint2 u = ((const uint2*)h1b)[(size_t)n0 * 4 + i];
        float f0 = bf2f((unsigned short)(u.x & 0xffff));
        float f1 = bf2f((unsigned short)(u.x >> 16));
        float f2 = bf2f((unsigned short)(u.y & 0xffff));
        float f3 = bf2f((unsigned short)(u.y >> 16));
        ((ushort4*)h1p)[(size_t)n0 * 4 + i] =
            make_ushort4(f2bf(f0 * dv), f2bf(f1 * dv), f2bf(f2 * dv), f2bf(f3 * dv));
    }
    if (bk == 0 && t == 0) offs[N] = E;
}

// gather1: 16 lanes/node; per load instr the group covers 2 edges (8 lanes x
// uint = 2 bf16 feats each); 32 edges per iteration; cross-half shfl_xor reduce.
// h2p[c] = bf16( dinv[c]*relu( dinv[c]*(sum h1p[src] + h1p[c]) + b1 ) )
__global__ __launch_bounds__(TPB) void gather1_kernel(const int* __restrict__ csr,
                                                      const int* __restrict__ offs,
                                                      const unsigned short* __restrict__ h1p,
                                                      const float* __restrict__ dinv,
                                                      const float* __restrict__ b1,
                                                      unsigned short* __restrict__ h2p, int N) {
    int t = threadIdx.x;
    int c = blockIdx.x * 16 + (t >> 4);
    int lane = t & 15;
    int half = lane >> 3;                    // which edge of the pair
    int kk = lane & 7;                       // feature pair: 2kk, 2kk+1
    if (c >= N) return;
    int p0 = offs[c], p1 = offs[c + 1];
    float a0 = 0.f, a1 = 0.f;
    for (int p = p0; p < p1; p += 32) {
        int s_lo = csr[min(p + lane, p1 - 1)];
        int s_hi = csr[min(p + 16 + lane, p1 - 1)];
        int rem = p1 - p;
        unsigned int u[16];
#pragma unroll
        for (int j = 0; j < 8; ++j) {
            int sj = __shfl(s_lo, 2 * j + half, 16);
            u[j] = *(const unsigned int*)&h1p[(size_t)sj * 16 + 2 * kk];
        }
#pragma unroll
        for (int j = 8; j < 16; ++j) {
            int sj = __shfl(s_hi, 2 * j + half - 16, 16);
            u[j] = *(const unsigned int*)&h1p[(size_t)sj * 16 + 2 * kk];
        }
#pragma unroll
        for (int j = 0; j < 16; ++j) {
            bool ok = (2 * j + half) < rem;
            a0 += ok ? bf2f((unsigned short)(u[j] & 0xffff)) : 0.f;
            a1 += ok ? bf2f((unsigned short)(u[j] >> 16)) : 0.f;
        }
    }
    a0 += __shfl_xor(a0, 8, 16);
    a1 += __shfl_xor(a1, 8, 16);
    if (half == 0) {
        float dc = dinv[c];
        unsigned int us = *(const unsigned int*)&h1p[(size_t)c * 16 + 2 * kk];
        float s0 = bf2f((unsigned short)(us & 0xffff));
        float s1 = bf2f((unsigned short)(us >> 16));
        float r0 = fmaf(dc, a0 + s0, b1[2 * kk]);
        float r1 = fmaf(dc, a1 + s1, b1[2 * kk + 1]);
        r0 = dc * fmaxf(r0, 0.f);
        r1 = dc * fmaxf(r1, 0.f);
        unsigned int w = (unsigned int)f2bf(r0) | ((unsigned int)f2bf(r1) << 16);
        *(unsigned int*)&h2p[(size_t)c * 16 + 2 * kk] = w;
    }
}

// gather2f: fused gather2 + W2 matmul + sorted-batch pooling.  Block = 64 nodes.
// Phase 1: 16 groups x 16 lanes gather a2 rows (4 nodes/group, uint-packed
// loads as in gather1) into LDS asT.
// Phase 2: wave w: 64 lanes = output dims, 16 nodes from asT, W2 slice in regs,
//          run-accumulate; uniform-batch blocks pool in LDS, flush 64 atomics.
__global__ __launch_bounds__(TPB) void gather2f_kernel(
        const int* __restrict__ csr, const int* __restrict__ offs,
        const unsigned short* __restrict__ h2p, const float* __restrict__ dinv,
        const float* __restrict__ W2, const float* __restrict__ b2,
        const int* __restrict__ batch, float* __restrict__ out, int N) {
    __shared__ float w2s[16 * 64];
    __shared__ float asT[64 * 17];
    __shared__ float pool[64];
    int t = threadIdx.x;
    for (int i = t; i < 16 * 64; i += TPB) w2s[i] = W2[i];
    if (t < 64) pool[t] = 0.f;

    int n0 = blockIdx.x * 64;
    int nLast = min(n0 + 63, N - 1);
    int g0 = batch[n0];
    bool uniform = (batch[nLast] == g0);     // batch sorted

    // phase 1: gather (4 nodes per 16-lane group)
    int grp = t >> 4, lane = t & 15;
    int half = lane >> 3, kk = lane & 7;
#pragma unroll 1
    for (int it = 0; it < 4; ++it) {
        int m = grp * 4 + it;
        int c = n0 + m;
        if (c < N) {
            int p0 = offs[c], p1 = offs[c + 1];
            float a0 = 0.f, a1 = 0.f;
            for (int p = p0; p < p1; p += 32) {
                int s_lo = csr[min(p + lane, p1 - 1)];
                int s_hi = csr[min(p + 16 + lane, p1 - 1)];
                int rem = p1 - p;
                unsigned int u[16];
#pragma unroll
                for (int j = 0; j < 8; ++j) {
                    int sj = __shfl(s_lo, 2 * j + half, 16);
                    u[j] = *(const unsigned int*)&h2p[(size_t)sj * 16 + 2 * kk];
                }
#pragma unroll
                for (int j = 8; j < 16; ++j) {
                    int sj = __shfl(s_hi, 2 * j + half - 16, 16);
                    u[j] = *(const unsigned int*)&h2p[(size_t)sj * 16 + 2 * kk];
                }
#pragma unroll
                for (int j = 0; j < 16; ++j) {
                    bool ok = (2 * j + half) < rem;
                    a0 += ok ? bf2f((unsigned short)(u[j] & 0xffff)) : 0.f;
                    a1 += ok ? bf2f((unsigned short)(u[j] >> 16)) : 0.f;
                }
            }
            a0 += __shfl_xor(a0, 8, 16);
            a1 += __shfl_xor(a1, 8, 16);
            if (half == 0) {
                float dc = dinv[c];
                unsigned int us = *(const unsigned int*)&h2p[(size_t)c * 16 + 2 * kk];
                float s0 = bf2f((unsigned short)(us & 0xffff));
                float s1 = bf2f((unsigned short)(us >> 16));
                asT[m * 17 + 2 * kk]     = dc * (a0 + s0);
                asT[m * 17 + 2 * kk + 1] = dc * (a1 + s1);
            }
        }
    }
    __syncthreads();

    // phase 2: wave w covers nodes n0+16w .. n0+16w+15
    int wave = t >> 6, j = t & 63;
    float w2reg[16];
#pragma unroll
    for (int kx = 0; kx < 16; ++kx) w2reg[kx] = w2s[kx * 64 + j];
    float b2j = b2[j];
    float val = 0.f;
    int g_cur = -1;
#pragma unroll 1
    for (int mi = 0; mi < 16; ++mi) {
        int m = wave * 16 + mi;
        int c = n0 + m;
        if (c >= N) break;
        const float* ar = &asT[m * 17];
        float y = b2j;
#pragma unroll
        for (int kx = 0; kx < 16; ++kx) y = fmaf(ar[kx], w2reg[kx], y);
        if (uniform) {
            val += y;
        } else {
            int g = batch[c];
            if (g != g_cur) {
                if (g_cur >= 0) atomicAdd(&out[(size_t)g_cur * 64 + j], val);
                val = 0.f;
                g_cur = g;
            }
            val += y;
        }
    }
    if (uniform) {
        atomicAdd(&pool[j], val);            // LDS, 4-way per address
        __syncthreads();
        if (t < 64) atomicAdd(&out[(size_t)g0 * 64 + t], pool[t]);
    } else {
        if (g_cur >= 0) atomicAdd(&out[(size_t)g_cur * 64 + j], val);
    }
}

static inline size_t align64(size_t v) { return (v + 63) & ~(size_t)63; }

extern "C" void kernel_launch(void* const* d_in, const int* in_sizes, int n_in,
                              void* d_out, int out_size, void* d_ws, size_t ws_size,
                              hipStream_t stream) {
    const float* x     = (const float*)d_in[0];
    const int*   ei    = (const int*)d_in[1];
    const int*   batch = (const int*)d_in[2];
    const float* W1    = (const float*)d_in[3];
    const float* b1    = (const float*)d_in[4];
    const float* W2    = (const float*)d_in[5];
    const float* b2    = (const float*)d_in[6];

    const int N = in_sizes[0] / 128;
    const int E = in_sizes[1] / 2;
    const int* row = ei;        // edge_index[0]
    const int* col = ei + E;    // edge_index[1]

    const int NBLK  = (E + CHUNK - 1) / CHUNK;       // 782
    const int NBUCK = (N + NPB - 1) / NPB;           // 391 (<=512)
    const int L     = NBUCK * NBLK;                  // 305762
    const int NBS   = (L + TPB - 1) / TPB;           // 1195 (<=2048 for scan2)
    const int NBG   = (N + TPB - 1) / TPB;           // 782

    char* p = (char*)d_ws;
    int*            counts   = (int*)p;            p += align64((size_t)L * 4);
    int*            bsum     = (int*)p;            p += align64(2048 * 4);
    int*            bucketed = (int*)p;            p += align64((size_t)E * 4);
    int*            csr      = (int*)p;            p += align64((size_t)E * 4);
    int*            offs     = (int*)p;            p += align64((size_t)(N + 1) * 4);
    float*          dinv     = (float*)p;          p += align64((size_t)N * 4);
    unsigned short* h1b      = (unsigned short*)p; p += align64((size_t)N * 16 * 2);
    unsigned short* h1p      = (unsigned short*)p; p += align64((size_t)N * 16 * 2);
    unsigned short* h2p      = (unsigned short*)p; p += align64((size_t)N * 16 * 2);
    float*          out      = (float*)d_out;

    hipMemsetAsync(out, 0, (size_t)out_size * sizeof(float), stream);

    hist_kernel<<<NBLK, TPB, 0, stream>>>(col, counts, E, NBLK, NBUCK);
    scan1_kernel<<<NBS, TPB, 0, stream>>>(counts, counts, bsum, L);
    scan2_kernel<<<1, 1024, 0, stream>>>(bsum, NBS);
    s1c_gemm_kernel<<<NBLK + NBG, TPB, 0, stream>>>(row, col, counts, bsum,
                                                    E, NBLK, NBUCK,
                                                    bucketed, x, W1, h1b, N, NBG);
    sort_kernel<<<NBUCK, TPB, 0, stream>>>(bucketed, counts, bsum, E, NBLK, NBUCK,
                                           csr, offs, dinv, h1b, h1p, N);
    gather1_kernel<<<(N + 15) / 16, TPB, 0, stream>>>(csr, offs, h1p, dinv, b1, h2p, N);
    gather2f_kernel<<<(N + 63) / 64, TPB, 0, stream>>>(csr, offs, h2p, dinv,
                                                       W2, b2, batch, out, N);
}